// Round 5
// baseline (91.737 us; speedup 1.0000x reference)
//
#include <hip/hip_runtime.h>
#include <hip/hip_bf16.h>

#define SUBS  64
#define THIST 200
#define BT    128              // conv rows per block
#define NPAIR (THIST / 2)      // 100 kernel tap-pairs
#define WROW  165              // LDS words per s-row (164 pairs + 1 pad, odd -> conflict-free)

typedef _Float16 h2    __attribute__((ext_vector_type(2)));
typedef _Float16 f16x8 __attribute__((ext_vector_type(8)));
typedef float    f32x4 __attribute__((ext_vector_type(4)));

union uh2 { uint u; h2 h; };

__device__ inline short f2hs(float v) {
    union { _Float16 h; short s; } u; u.h = (_Float16)v; return u.s;
}

// ---------------------------------------------------------------------------
// Kernel 1: reversed, pre-paired taps.
// krp[p*64+s] = pack(kern[s][199-2p], kern[s][198-2p]) as 2x f16.
// ---------------------------------------------------------------------------
__device__ inline float kval(int k, float del, const float* Ks, const float* tau) {
    float t = fmaxf((float)k - del, 0.0f);
    float v = 0.0f;
    #pragma unroll
    for (int b = 0; b < 3; ++b) {
        float tt = t / __expf(tau[b]);
        v = fmaf(tt * __expf(-tt), Ks[b], v);
    }
    return v;
}

__global__ __launch_bounds__(256) void k_taps(
    const float* __restrict__ K_spike, const float* __restrict__ tau_spike,
    const float* __restrict__ delta_spike, uint* __restrict__ krp)
{
    int idx = blockIdx.x * 256 + threadIdx.x;
    if (idx >= NPAIR * SUBS) return;
    int p = idx >> 6, s = idx & 63;
    float del = delta_spike[s];
    float Ks[3] = { K_spike[s*3], K_spike[s*3+1], K_spike[s*3+2] };
    float tl[3] = { tau_spike[0], tau_spike[1], tau_spike[2] };
    ushort lo = (ushort)f2hs(kval(199 - 2*p, del, Ks, tl));
    ushort hi = (ushort)f2hs(kval(198 - 2*p, del, Ks, tl));
    krp[p * 64 + s] = (uint)lo | ((uint)hi << 16);
}

// ---------------------------------------------------------------------------
// Kernel 2 (f16 MFMA): Zc = Z @ C^T, base = S + theta + Y @ C^T  (f16 out)
// ---------------------------------------------------------------------------
__global__ __launch_bounds__(256, 4) void k_zc_base(
    const float* __restrict__ Z, const float* __restrict__ Y,
    const float* __restrict__ S, const float* __restrict__ C,
    const float* __restrict__ theta,
    _Float16* __restrict__ Zc, _Float16* __restrict__ base, int T)
{
    __shared__ _Float16 bnc[4][16 * 68];      // per-wave bounce tile, stride 68
    const int tid  = threadIdx.x;
    const int lane = tid & 63;
    const int wv   = tid >> 6;
    const int lr   = lane & 15;
    const int lg   = lane >> 4;
    const int tblk = blockIdx.x * 128 + wv * 32;
    _Float16* bw = &bnc[wv][0];

    f16x8 bfr[4][2];
    #pragma unroll
    for (int nt = 0; nt < 4; ++nt) {
        #pragma unroll
        for (int ks = 0; ks < 2; ++ks) {
            const float* p = &C[(lr + 16 * nt) * 64 + ks * 32 + lg * 8];
            float4 a = *(const float4*)p;
            float4 b = *(const float4*)(p + 4);
            f16x8 f;
            f[0]=(_Float16)a.x; f[1]=(_Float16)a.y; f[2]=(_Float16)a.z; f[3]=(_Float16)a.w;
            f[4]=(_Float16)b.x; f[5]=(_Float16)b.y; f[6]=(_Float16)b.z; f[7]=(_Float16)b.w;
            bfr[nt][ks] = f;
        }
    }

    const float4 th = *(const float4*)&theta[lr * 4];

    #pragma unroll
    for (int g = 0; g < 2; ++g) {
        const int t0 = tblk + g * 16;
        const int rowA = t0 + lr;
        const bool okA = rowA < T;
        f16x8 az[2], ay[2];
        #pragma unroll
        for (int ks = 0; ks < 2; ++ks) {
            float4 z0 = {0,0,0,0}, z1 = z0, y0 = z0, y1 = z0;
            if (okA) {
                const float* pz = &Z[(size_t)rowA * 64 + ks * 32 + lg * 8];
                const float* py = &Y[(size_t)rowA * 64 + ks * 32 + lg * 8];
                z0 = *(const float4*)pz;  z1 = *(const float4*)(pz + 4);
                y0 = *(const float4*)py;  y1 = *(const float4*)(py + 4);
            }
            f16x8 fz, fy;
            fz[0]=(_Float16)z0.x; fz[1]=(_Float16)z0.y; fz[2]=(_Float16)z0.z; fz[3]=(_Float16)z0.w;
            fz[4]=(_Float16)z1.x; fz[5]=(_Float16)z1.y; fz[6]=(_Float16)z1.z; fz[7]=(_Float16)z1.w;
            fy[0]=(_Float16)y0.x; fy[1]=(_Float16)y0.y; fy[2]=(_Float16)y0.z; fy[3]=(_Float16)y0.w;
            fy[4]=(_Float16)y1.x; fy[5]=(_Float16)y1.y; fy[6]=(_Float16)y1.z; fy[7]=(_Float16)y1.w;
            az[ks] = fz;  ay[ks] = fy;
        }

        f32x4 accZ[4], accY[4];
        #pragma unroll
        for (int nt = 0; nt < 4; ++nt) { accZ[nt] = (f32x4){0,0,0,0}; accY[nt] = (f32x4){0,0,0,0}; }
        #pragma unroll
        for (int nt = 0; nt < 4; ++nt) {
            #pragma unroll
            for (int ks = 0; ks < 2; ++ks) {
                accZ[nt] = __builtin_amdgcn_mfma_f32_16x16x32_f16(az[ks], bfr[nt][ks], accZ[nt], 0, 0, 0);
                accY[nt] = __builtin_amdgcn_mfma_f32_16x16x32_f16(ay[ks], bfr[nt][ks], accY[nt], 0, 0, 0);
            }
        }

        #pragma unroll
        for (int nt = 0; nt < 4; ++nt)
            #pragma unroll
            for (int r = 0; r < 4; ++r)
                bw[(lg * 4 + r) * 68 + lr + 16 * nt] = (_Float16)accZ[nt][r];
        __builtin_amdgcn_wave_barrier();
        #pragma unroll
        for (int i = 0; i < 4; ++i) {
            const int row = i * 4 + lg;
            const int t = t0 + row;
            if (t < T)
                *(ushort4*)&Zc[(size_t)t * 64 + lr * 4] =
                    *(const ushort4*)&bw[row * 68 + lr * 4];
        }
        __builtin_amdgcn_wave_barrier();

        #pragma unroll
        for (int nt = 0; nt < 4; ++nt)
            #pragma unroll
            for (int r = 0; r < 4; ++r)
                bw[(lg * 4 + r) * 68 + lr + 16 * nt] = (_Float16)accY[nt][r];
        __builtin_amdgcn_wave_barrier();
        #pragma unroll
        for (int i = 0; i < 4; ++i) {
            const int row = i * 4 + lg;
            const int t = t0 + row;
            if (t < T) {
                const float4 sv = *(const float4*)&S[(size_t)t * 64 + lr * 4];
                union { _Float16 h[4]; ushort4 u; } pb;
                const _Float16* yb = &bw[row * 68 + lr * 4];
                pb.h[0] = (_Float16)((float)yb[0] + sv.x + th.x);
                pb.h[1] = (_Float16)((float)yb[1] + sv.y + th.y);
                pb.h[2] = (_Float16)((float)yb[2] + sv.z + th.z);
                pb.h[3] = (_Float16)((float)yb[3] + sv.w + th.w);
                *(ushort4*)&base[(size_t)t * 64 + lr * 4] = pb.u;
            }
        }
        __builtin_amdgcn_wave_barrier();
    }
}

// ---------------------------------------------------------------------------
// Kernel 3 (dot2 FIR, software-pipelined):
//   filtered[t,s] = sum_d kern[s][d-1] * Zc[t-d][s]
//   out = sigmoid(base + filtered) * W + V_o
// 512 thr = 8 waves x 16 rows; lane = s. LDS: Zc window transposed [s][time].
// Pipeline: window ds_reads batch-hoisted per group; taps double-buffered
// one group ahead; base preloaded at kernel entry.
// ---------------------------------------------------------------------------
__global__ __launch_bounds__(512, 6) void k_conv(
    const uint* __restrict__ krp, const _Float16* __restrict__ Zc,
    const _Float16* __restrict__ base, const float* __restrict__ W,
    const float* __restrict__ Vo, float* __restrict__ out, int T)
{
    __shared__ uint wzu[SUBS * WROW];          // 42240 B
    ushort* wzh = (ushort*)wzu;
    const int tid = threadIdx.x;
    const int t0  = blockIdx.x * BT;

    const int s   = tid & 63;
    const int wid = tid >> 6;
    const int rt  = wid * 16;
    const int q0  = wid * 8;

    // ---- preload base rows for this thread (latency hides under everything)
    float xb[16];
    #pragma unroll
    for (int r = 0; r < 16; ++r) {
        const int t = t0 + rt + r;
        xb[r] = (t < T) ? (float)base[(size_t)t * SUBS + s] : 0.0f;
    }

    {   // stage + transpose Zc rows [t0-200, t0+BT): global [t][s] -> LDS [s][t]
        const ushort4* src = (const ushort4*)Zc;
        const int n = (BT + THIST) * (SUBS / 4);
        for (int i = tid; i < n; i += 512) {
            int r  = i >> 4;
            int c4 = i & 15;
            int g  = t0 - THIST + r;
            ushort4 v = make_ushort4(0, 0, 0, 0);
            if (g >= 0 && g < T) v = src[(size_t)g * 16 + c4];
            wzh[(4 * c4 + 0) * 2 * WROW + r] = v.x;
            wzh[(4 * c4 + 1) * 2 * WROW + r] = v.y;
            wzh[(4 * c4 + 2) * 2 * WROW + r] = v.z;
            wzh[(4 * c4 + 3) * 2 * WROW + r] = v.w;
        }
    }
    __syncthreads();

    const uint* wp = &wzu[s * WROW];

    float acc[16];
    #pragma unroll
    for (int r = 0; r < 16; ++r) acc[r] = 0.f;

    uint E[8], O[8];
    #pragma unroll
    for (int i = 0; i < 8; ++i) E[i] = wp[q0 + i];
    #pragma unroll
    for (int i = 0; i < 7; ++i) O[i] = __builtin_amdgcn_alignbit(E[i + 1], E[i], 16);

    uint kvc[8], kvn[8];
    #pragma unroll
    for (int j = 0; j < 8; ++j) kvc[j] = krp[j * 64 + s];

    // step P (=0..99): acc[2i]   += dot2(kp[P], E-pair), acc[2i+1] += dot2(kp[P], O-pair)
    #pragma unroll 1
    for (int g = 0; g < 12; ++g) {
        // prefetch NEXT group's taps (global, L1/L2) - consumed next iteration
        if (g < 11) {
            #pragma unroll
            for (int j = 0; j < 8; ++j) kvn[j] = krp[((g + 1) * 8 + j) * 64 + s];
        } else {
            #pragma unroll
            for (int j = 0; j < 4; ++j) kvn[j] = krp[(96 + j) * 64 + s];
        }
        // batch-hoisted window reads for this group
        uint nE[8];
        #pragma unroll
        for (int j = 0; j < 8; ++j) nE[j] = wp[q0 + g * 8 + 8 + j];

        #pragma unroll
        for (int j = 0; j < 8; ++j) {
            O[(j + 7) & 7] = __builtin_amdgcn_alignbit(nE[j], E[(j + 7) & 7], 16);
            uh2 kk; kk.u = kvc[j];
            #pragma unroll
            for (int i = 0; i < 8; ++i) {
                uh2 e; e.u = E[(j + i) & 7];
                uh2 o; o.u = O[(j + i) & 7];
                acc[2 * i]     = __builtin_amdgcn_fdot2(kk.h, e.h, acc[2 * i],     false);
                acc[2 * i + 1] = __builtin_amdgcn_fdot2(kk.h, o.h, acc[2 * i + 1], false);
            }
            E[j & 7] = nE[j];
        }
        #pragma unroll
        for (int j = 0; j < 8; ++j) kvc[j] = kvn[j];
    }
    {   // tail: pairs 96..99 (taps already in kvc[0..3])
        uint nE[4];
        #pragma unroll
        for (int j = 0; j < 4; ++j) nE[j] = wp[q0 + 96 + 8 + j];
        #pragma unroll
        for (int j = 0; j < 4; ++j) {
            O[(j + 7) & 7] = __builtin_amdgcn_alignbit(nE[j], E[(j + 7) & 7], 16);
            uh2 kk; kk.u = kvc[j];
            #pragma unroll
            for (int i = 0; i < 8; ++i) {
                uh2 e; e.u = E[(j + i) & 7];
                uh2 o; o.u = O[(j + i) & 7];
                acc[2 * i]     = __builtin_amdgcn_fdot2(kk.h, e.h, acc[2 * i],     false);
                acc[2 * i + 1] = __builtin_amdgcn_fdot2(kk.h, o.h, acc[2 * i + 1], false);
            }
            E[j & 7] = nE[j];
        }
    }

    const float wsub = W[s];
    const float vo   = Vo[0];
    #pragma unroll
    for (int r = 0; r < 16; ++r) {
        const int t = t0 + rt + r;
        if (t < T) {
            float xin = xb[r] + acc[r];
            float sig = 1.0f / (1.0f + __expf(-xin));
            out[(size_t)t * SUBS + s] = fmaf(sig, wsub, vo);
        }
    }
}

// ---------------------------------------------------------------------------
extern "C" void kernel_launch(void* const* d_in, const int* in_sizes, int n_in,
                              void* d_out, int out_size, void* d_ws, size_t ws_size,
                              hipStream_t stream)
{
    const float* S     = (const float*)d_in[0];
    const float* Y     = (const float*)d_in[1];
    const float* Z     = (const float*)d_in[2];
    const float* C     = (const float*)d_in[3];
    const float* Vo    = (const float*)d_in[4];
    const float* W     = (const float*)d_in[5];
    const float* theta = (const float*)d_in[6];
    const float* K     = (const float*)d_in[7];
    const float* tau   = (const float*)d_in[8];
    const float* delta = (const float*)d_in[9];
    const int T = in_sizes[0] / SUBS;

    uint*      krp  = (uint*)d_ws;                                  // 25600 B
    _Float16*  Zc   = (_Float16*)((char*)d_ws + 32768);             // T*64*2 B
    _Float16*  base = (_Float16*)((char*)d_ws + 32768 + (size_t)T * SUBS * 2);

    k_taps<<<(NPAIR * SUBS + 255) / 256, 256, 0, stream>>>(K, tau, delta, krp);
    k_zc_base<<<(T + 127) / 128, 256, 0, stream>>>(Z, Y, S, C, theta, Zc, base, T);
    k_conv<<<(T + BT - 1) / BT, 512, 0, stream>>>(krp, Zc, base, W, Vo, (float*)d_out, T);
}

// Round 6
// 79.307 us; speedup vs baseline: 1.1567x; 1.1567x over previous
//
#include <hip/hip_runtime.h>
#include <hip/hip_bf16.h>

#define SUBS  64
#define THIST 200
#define BT    128              // conv rows per block
#define NPAIR (THIST / 2)      // 100 kernel tap-pairs
#define WROW  165              // LDS words per s-row (164 pairs + 1 pad, odd -> conflict-free)

typedef _Float16 h2    __attribute__((ext_vector_type(2)));
typedef _Float16 f16x8 __attribute__((ext_vector_type(8)));
typedef float    f32x4 __attribute__((ext_vector_type(4)));

union uh2 { uint u; h2 h; };

__device__ inline short f2hs(float v) {
    union { _Float16 h; short s; } u; u.h = (_Float16)v; return u.s;
}

// ---------------------------------------------------------------------------
// Kernel 1: reversed, pre-paired taps.
// krp[p*64+s] = pack(kern[s][199-2p], kern[s][198-2p]) as 2x f16.
// ---------------------------------------------------------------------------
__device__ inline float kval(int k, float del, const float* Ks, const float* tau) {
    float t = fmaxf((float)k - del, 0.0f);
    float v = 0.0f;
    #pragma unroll
    for (int b = 0; b < 3; ++b) {
        float tt = t / __expf(tau[b]);
        v = fmaf(tt * __expf(-tt), Ks[b], v);
    }
    return v;
}

__global__ __launch_bounds__(256) void k_taps(
    const float* __restrict__ K_spike, const float* __restrict__ tau_spike,
    const float* __restrict__ delta_spike, uint* __restrict__ krp)
{
    int idx = blockIdx.x * 256 + threadIdx.x;
    if (idx >= NPAIR * SUBS) return;
    int p = idx >> 6, s = idx & 63;
    float del = delta_spike[s];
    float Ks[3] = { K_spike[s*3], K_spike[s*3+1], K_spike[s*3+2] };
    float tl[3] = { tau_spike[0], tau_spike[1], tau_spike[2] };
    ushort lo = (ushort)f2hs(kval(199 - 2*p, del, Ks, tl));
    ushort hi = (ushort)f2hs(kval(198 - 2*p, del, Ks, tl));
    krp[p * 64 + s] = (uint)lo | ((uint)hi << 16);
}

// ---------------------------------------------------------------------------
// Kernel 2 (f16 MFMA): Zc = Z @ C^T, base = S + theta + Y @ C^T  (f16 out)
// ---------------------------------------------------------------------------
__global__ __launch_bounds__(256, 4) void k_zc_base(
    const float* __restrict__ Z, const float* __restrict__ Y,
    const float* __restrict__ S, const float* __restrict__ C,
    const float* __restrict__ theta,
    _Float16* __restrict__ Zc, _Float16* __restrict__ base, int T)
{
    __shared__ _Float16 bnc[4][16 * 68];      // per-wave bounce tile, stride 68
    const int tid  = threadIdx.x;
    const int lane = tid & 63;
    const int wv   = tid >> 6;
    const int lr   = lane & 15;
    const int lg   = lane >> 4;
    const int tblk = blockIdx.x * 128 + wv * 32;
    _Float16* bw = &bnc[wv][0];

    f16x8 bfr[4][2];
    #pragma unroll
    for (int nt = 0; nt < 4; ++nt) {
        #pragma unroll
        for (int ks = 0; ks < 2; ++ks) {
            const float* p = &C[(lr + 16 * nt) * 64 + ks * 32 + lg * 8];
            float4 a = *(const float4*)p;
            float4 b = *(const float4*)(p + 4);
            f16x8 f;
            f[0]=(_Float16)a.x; f[1]=(_Float16)a.y; f[2]=(_Float16)a.z; f[3]=(_Float16)a.w;
            f[4]=(_Float16)b.x; f[5]=(_Float16)b.y; f[6]=(_Float16)b.z; f[7]=(_Float16)b.w;
            bfr[nt][ks] = f;
        }
    }

    const float4 th = *(const float4*)&theta[lr * 4];

    #pragma unroll
    for (int g = 0; g < 2; ++g) {
        const int t0 = tblk + g * 16;
        const int rowA = t0 + lr;
        const bool okA = rowA < T;
        f16x8 az[2], ay[2];
        #pragma unroll
        for (int ks = 0; ks < 2; ++ks) {
            float4 z0 = {0,0,0,0}, z1 = z0, y0 = z0, y1 = z0;
            if (okA) {
                const float* pz = &Z[(size_t)rowA * 64 + ks * 32 + lg * 8];
                const float* py = &Y[(size_t)rowA * 64 + ks * 32 + lg * 8];
                z0 = *(const float4*)pz;  z1 = *(const float4*)(pz + 4);
                y0 = *(const float4*)py;  y1 = *(const float4*)(py + 4);
            }
            f16x8 fz, fy;
            fz[0]=(_Float16)z0.x; fz[1]=(_Float16)z0.y; fz[2]=(_Float16)z0.z; fz[3]=(_Float16)z0.w;
            fz[4]=(_Float16)z1.x; fz[5]=(_Float16)z1.y; fz[6]=(_Float16)z1.z; fz[7]=(_Float16)z1.w;
            fy[0]=(_Float16)y0.x; fy[1]=(_Float16)y0.y; fy[2]=(_Float16)y0.z; fy[3]=(_Float16)y0.w;
            fy[4]=(_Float16)y1.x; fy[5]=(_Float16)y1.y; fy[6]=(_Float16)y1.z; fy[7]=(_Float16)y1.w;
            az[ks] = fz;  ay[ks] = fy;
        }

        f32x4 accZ[4], accY[4];
        #pragma unroll
        for (int nt = 0; nt < 4; ++nt) { accZ[nt] = (f32x4){0,0,0,0}; accY[nt] = (f32x4){0,0,0,0}; }
        #pragma unroll
        for (int nt = 0; nt < 4; ++nt) {
            #pragma unroll
            for (int ks = 0; ks < 2; ++ks) {
                accZ[nt] = __builtin_amdgcn_mfma_f32_16x16x32_f16(az[ks], bfr[nt][ks], accZ[nt], 0, 0, 0);
                accY[nt] = __builtin_amdgcn_mfma_f32_16x16x32_f16(ay[ks], bfr[nt][ks], accY[nt], 0, 0, 0);
            }
        }

        #pragma unroll
        for (int nt = 0; nt < 4; ++nt)
            #pragma unroll
            for (int r = 0; r < 4; ++r)
                bw[(lg * 4 + r) * 68 + lr + 16 * nt] = (_Float16)accZ[nt][r];
        __builtin_amdgcn_wave_barrier();
        #pragma unroll
        for (int i = 0; i < 4; ++i) {
            const int row = i * 4 + lg;
            const int t = t0 + row;
            if (t < T)
                *(ushort4*)&Zc[(size_t)t * 64 + lr * 4] =
                    *(const ushort4*)&bw[row * 68 + lr * 4];
        }
        __builtin_amdgcn_wave_barrier();

        #pragma unroll
        for (int nt = 0; nt < 4; ++nt)
            #pragma unroll
            for (int r = 0; r < 4; ++r)
                bw[(lg * 4 + r) * 68 + lr + 16 * nt] = (_Float16)accY[nt][r];
        __builtin_amdgcn_wave_barrier();
        #pragma unroll
        for (int i = 0; i < 4; ++i) {
            const int row = i * 4 + lg;
            const int t = t0 + row;
            if (t < T) {
                const float4 sv = *(const float4*)&S[(size_t)t * 64 + lr * 4];
                union { _Float16 h[4]; ushort4 u; } pb;
                const _Float16* yb = &bw[row * 68 + lr * 4];
                pb.h[0] = (_Float16)((float)yb[0] + sv.x + th.x);
                pb.h[1] = (_Float16)((float)yb[1] + sv.y + th.y);
                pb.h[2] = (_Float16)((float)yb[2] + sv.z + th.z);
                pb.h[3] = (_Float16)((float)yb[3] + sv.w + th.w);
                *(ushort4*)&base[(size_t)t * 64 + lr * 4] = pb.u;
            }
        }
        __builtin_amdgcn_wave_barrier();
    }
}

// ---------------------------------------------------------------------------
// Kernel 3 (dot2 FIR, software-pipelined, no spill):
//   filtered[t,s] = sum_d kern[s][d-1] * Zc[t-d][s]
//   out = sigmoid(base + filtered) * W + V_o
// 512 thr = 8 waves x 16 rows; lane = s. LDS: Zc window transposed [s][time].
// Pipeline: taps double-buffered one group ahead (kvc/kvn); window ds_reads
// batch-hoisted per group (nE). Base loaded in epilogue.
// launch_bounds(512,3): (512,6) empirically pins VGPR=40 and spills (R5:
// WRITE_SIZE 25000->86000 KB). Live set ~72 VGPR; LDS still limits to
// 3 blocks/CU = 6 waves/SIMD.
// ---------------------------------------------------------------------------
__global__ __launch_bounds__(512, 3) void k_conv(
    const uint* __restrict__ krp, const _Float16* __restrict__ Zc,
    const _Float16* __restrict__ base, const float* __restrict__ W,
    const float* __restrict__ Vo, float* __restrict__ out, int T)
{
    __shared__ uint wzu[SUBS * WROW];          // 42240 B
    ushort* wzh = (ushort*)wzu;
    const int tid = threadIdx.x;
    const int t0  = blockIdx.x * BT;

    {   // stage + transpose Zc rows [t0-200, t0+BT): global [t][s] -> LDS [s][t]
        const ushort4* src = (const ushort4*)Zc;
        const int n = (BT + THIST) * (SUBS / 4);
        for (int i = tid; i < n; i += 512) {
            int r  = i >> 4;
            int c4 = i & 15;
            int g  = t0 - THIST + r;
            ushort4 v = make_ushort4(0, 0, 0, 0);
            if (g >= 0 && g < T) v = src[(size_t)g * 16 + c4];
            wzh[(4 * c4 + 0) * 2 * WROW + r] = v.x;
            wzh[(4 * c4 + 1) * 2 * WROW + r] = v.y;
            wzh[(4 * c4 + 2) * 2 * WROW + r] = v.z;
            wzh[(4 * c4 + 3) * 2 * WROW + r] = v.w;
        }
    }
    __syncthreads();

    const int s   = tid & 63;
    const int wid = tid >> 6;
    const int rt  = wid * 16;
    const int q0  = wid * 8;
    const uint* wp = &wzu[s * WROW];

    float acc[16];
    #pragma unroll
    for (int r = 0; r < 16; ++r) acc[r] = 0.f;

    uint E[8], O[8];
    #pragma unroll
    for (int i = 0; i < 8; ++i) E[i] = wp[q0 + i];
    #pragma unroll
    for (int i = 0; i < 7; ++i) O[i] = __builtin_amdgcn_alignbit(E[i + 1], E[i], 16);

    uint kvc[8], kvn[8];
    #pragma unroll
    for (int j = 0; j < 8; ++j) kvc[j] = krp[j * 64 + s];

    // step P (=0..99): acc[2i]   += dot2(kp[P], E-pair), acc[2i+1] += dot2(kp[P], O-pair)
    #pragma unroll 1
    for (int g = 0; g < 12; ++g) {
        // prefetch NEXT group's taps first (longest latency, consumed next iter)
        if (g < 11) {
            #pragma unroll
            for (int j = 0; j < 8; ++j) kvn[j] = krp[((g + 1) * 8 + j) * 64 + s];
        } else {
            #pragma unroll
            for (int j = 0; j < 4; ++j) kvn[j] = krp[(96 + j) * 64 + s];
        }
        // batch-hoisted window reads for this group
        uint nE[8];
        #pragma unroll
        for (int j = 0; j < 8; ++j) nE[j] = wp[q0 + g * 8 + 8 + j];

        #pragma unroll
        for (int j = 0; j < 8; ++j) {
            O[(j + 7) & 7] = __builtin_amdgcn_alignbit(nE[j], E[(j + 7) & 7], 16);
            uh2 kk; kk.u = kvc[j];
            #pragma unroll
            for (int i = 0; i < 8; ++i) {
                uh2 e; e.u = E[(j + i) & 7];
                uh2 o; o.u = O[(j + i) & 7];
                acc[2 * i]     = __builtin_amdgcn_fdot2(kk.h, e.h, acc[2 * i],     false);
                acc[2 * i + 1] = __builtin_amdgcn_fdot2(kk.h, o.h, acc[2 * i + 1], false);
            }
            E[j & 7] = nE[j];
        }
        #pragma unroll
        for (int j = 0; j < 8; ++j) kvc[j] = kvn[j];
    }
    {   // tail: pairs 96..99 (taps already in kvc[0..3])
        uint nE[4];
        #pragma unroll
        for (int j = 0; j < 4; ++j) nE[j] = wp[q0 + 96 + 8 + j];
        #pragma unroll
        for (int j = 0; j < 4; ++j) {
            O[(j + 7) & 7] = __builtin_amdgcn_alignbit(nE[j], E[(j + 7) & 7], 16);
            uh2 kk; kk.u = kvc[j];
            #pragma unroll
            for (int i = 0; i < 8; ++i) {
                uh2 e; e.u = E[(j + i) & 7];
                uh2 o; o.u = O[(j + i) & 7];
                acc[2 * i]     = __builtin_amdgcn_fdot2(kk.h, e.h, acc[2 * i],     false);
                acc[2 * i + 1] = __builtin_amdgcn_fdot2(kk.h, o.h, acc[2 * i + 1], false);
            }
            E[j & 7] = nE[j];
        }
    }

    const float wsub = W[s];
    const float vo   = Vo[0];
    #pragma unroll
    for (int r = 0; r < 16; ++r) {
        const int t = t0 + rt + r;
        if (t < T) {
            float xin = (float)base[(size_t)t * SUBS + s] + acc[r];
            float sig = 1.0f / (1.0f + __expf(-xin));
            out[(size_t)t * SUBS + s] = fmaf(sig, wsub, vo);
        }
    }
}

// ---------------------------------------------------------------------------
extern "C" void kernel_launch(void* const* d_in, const int* in_sizes, int n_in,
                              void* d_out, int out_size, void* d_ws, size_t ws_size,
                              hipStream_t stream)
{
    const float* S     = (const float*)d_in[0];
    const float* Y     = (const float*)d_in[1];
    const float* Z     = (const float*)d_in[2];
    const float* C     = (const float*)d_in[3];
    const float* Vo    = (const float*)d_in[4];
    const float* W     = (const float*)d_in[5];
    const float* theta = (const float*)d_in[6];
    const float* K     = (const float*)d_in[7];
    const float* tau   = (const float*)d_in[8];
    const float* delta = (const float*)d_in[9];
    const int T = in_sizes[0] / SUBS;

    uint*      krp  = (uint*)d_ws;                                  // 25600 B
    _Float16*  Zc   = (_Float16*)((char*)d_ws + 32768);             // T*64*2 B
    _Float16*  base = (_Float16*)((char*)d_ws + 32768 + (size_t)T * SUBS * 2);

    k_taps<<<(NPAIR * SUBS + 255) / 256, 256, 0, stream>>>(K, tau, delta, krp);
    k_zc_base<<<(T + 127) / 128, 256, 0, stream>>>(Z, Y, S, C, theta, Zc, base, T);
    k_conv<<<(T + BT - 1) / BT, 512, 0, stream>>>(krp, Zc, base, W, Vo, (float*)d_out, T);
}

// Round 7
// 76.259 us; speedup vs baseline: 1.2030x; 1.0400x over previous
//
#include <hip/hip_runtime.h>
#include <hip/hip_bf16.h>

#define SUBS  64
#define THIST 200
#define BT    128              // conv rows per block
#define NPAIR (THIST / 2)      // 100 kernel tap-pairs
#define WROW  165              // LDS words per s-row (164 pairs + 1 pad, odd -> conflict-free)

typedef _Float16 h2    __attribute__((ext_vector_type(2)));
typedef _Float16 f16x8 __attribute__((ext_vector_type(8)));
typedef float    f32x4 __attribute__((ext_vector_type(4)));

union uh2 { uint u; h2 h; };

__device__ inline short f2hs(float v) {
    union { _Float16 h; short s; } u; u.h = (_Float16)v; return u.s;
}

// ---------------------------------------------------------------------------
// Kernel 1: reversed, pre-paired taps, TRANSPOSED layout krt[s][p]:
// krt[s*100+p] = pack(kern[s][199-2p], kern[s][198-2p]) as 2x f16.
// Per-lane tap loads in k_conv are then contiguous 32B -> 2x dwordx4.
// ---------------------------------------------------------------------------
__device__ inline float kval(int k, float del, const float* Ks, const float* tau) {
    float t = fmaxf((float)k - del, 0.0f);
    float v = 0.0f;
    #pragma unroll
    for (int b = 0; b < 3; ++b) {
        float tt = t / __expf(tau[b]);
        v = fmaf(tt * __expf(-tt), Ks[b], v);
    }
    return v;
}

__global__ __launch_bounds__(256) void k_taps(
    const float* __restrict__ K_spike, const float* __restrict__ tau_spike,
    const float* __restrict__ delta_spike, uint* __restrict__ krt)
{
    int idx = blockIdx.x * 256 + threadIdx.x;
    if (idx >= NPAIR * SUBS) return;
    int p = idx >> 6, s = idx & 63;
    float del = delta_spike[s];
    float Ks[3] = { K_spike[s*3], K_spike[s*3+1], K_spike[s*3+2] };
    float tl[3] = { tau_spike[0], tau_spike[1], tau_spike[2] };
    ushort lo = (ushort)f2hs(kval(199 - 2*p, del, Ks, tl));
    ushort hi = (ushort)f2hs(kval(198 - 2*p, del, Ks, tl));
    krt[s * 100 + p] = (uint)lo | ((uint)hi << 16);
}

// ---------------------------------------------------------------------------
// Kernel 2 (f16 MFMA): Zc = Z @ C^T, base = S + theta + Y @ C^T  (f16 out)
// ---------------------------------------------------------------------------
__global__ __launch_bounds__(256, 4) void k_zc_base(
    const float* __restrict__ Z, const float* __restrict__ Y,
    const float* __restrict__ S, const float* __restrict__ C,
    const float* __restrict__ theta,
    _Float16* __restrict__ Zc, _Float16* __restrict__ base, int T)
{
    __shared__ _Float16 bnc[4][16 * 68];      // per-wave bounce tile, stride 68
    const int tid  = threadIdx.x;
    const int lane = tid & 63;
    const int wv   = tid >> 6;
    const int lr   = lane & 15;
    const int lg   = lane >> 4;
    const int tblk = blockIdx.x * 128 + wv * 32;
    _Float16* bw = &bnc[wv][0];

    f16x8 bfr[4][2];
    #pragma unroll
    for (int nt = 0; nt < 4; ++nt) {
        #pragma unroll
        for (int ks = 0; ks < 2; ++ks) {
            const float* p = &C[(lr + 16 * nt) * 64 + ks * 32 + lg * 8];
            float4 a = *(const float4*)p;
            float4 b = *(const float4*)(p + 4);
            f16x8 f;
            f[0]=(_Float16)a.x; f[1]=(_Float16)a.y; f[2]=(_Float16)a.z; f[3]=(_Float16)a.w;
            f[4]=(_Float16)b.x; f[5]=(_Float16)b.y; f[6]=(_Float16)b.z; f[7]=(_Float16)b.w;
            bfr[nt][ks] = f;
        }
    }

    const float4 th = *(const float4*)&theta[lr * 4];

    #pragma unroll
    for (int g = 0; g < 2; ++g) {
        const int t0 = tblk + g * 16;
        const int rowA = t0 + lr;
        const bool okA = rowA < T;
        f16x8 az[2], ay[2];
        #pragma unroll
        for (int ks = 0; ks < 2; ++ks) {
            float4 z0 = {0,0,0,0}, z1 = z0, y0 = z0, y1 = z0;
            if (okA) {
                const float* pz = &Z[(size_t)rowA * 64 + ks * 32 + lg * 8];
                const float* py = &Y[(size_t)rowA * 64 + ks * 32 + lg * 8];
                z0 = *(const float4*)pz;  z1 = *(const float4*)(pz + 4);
                y0 = *(const float4*)py;  y1 = *(const float4*)(py + 4);
            }
            f16x8 fz, fy;
            fz[0]=(_Float16)z0.x; fz[1]=(_Float16)z0.y; fz[2]=(_Float16)z0.z; fz[3]=(_Float16)z0.w;
            fz[4]=(_Float16)z1.x; fz[5]=(_Float16)z1.y; fz[6]=(_Float16)z1.z; fz[7]=(_Float16)z1.w;
            fy[0]=(_Float16)y0.x; fy[1]=(_Float16)y0.y; fy[2]=(_Float16)y0.z; fy[3]=(_Float16)y0.w;
            fy[4]=(_Float16)y1.x; fy[5]=(_Float16)y1.y; fy[6]=(_Float16)y1.z; fy[7]=(_Float16)y1.w;
            az[ks] = fz;  ay[ks] = fy;
        }

        f32x4 accZ[4], accY[4];
        #pragma unroll
        for (int nt = 0; nt < 4; ++nt) { accZ[nt] = (f32x4){0,0,0,0}; accY[nt] = (f32x4){0,0,0,0}; }
        #pragma unroll
        for (int nt = 0; nt < 4; ++nt) {
            #pragma unroll
            for (int ks = 0; ks < 2; ++ks) {
                accZ[nt] = __builtin_amdgcn_mfma_f32_16x16x32_f16(az[ks], bfr[nt][ks], accZ[nt], 0, 0, 0);
                accY[nt] = __builtin_amdgcn_mfma_f32_16x16x32_f16(ay[ks], bfr[nt][ks], accY[nt], 0, 0, 0);
            }
        }

        #pragma unroll
        for (int nt = 0; nt < 4; ++nt)
            #pragma unroll
            for (int r = 0; r < 4; ++r)
                bw[(lg * 4 + r) * 68 + lr + 16 * nt] = (_Float16)accZ[nt][r];
        __builtin_amdgcn_wave_barrier();
        #pragma unroll
        for (int i = 0; i < 4; ++i) {
            const int row = i * 4 + lg;
            const int t = t0 + row;
            if (t < T)
                *(ushort4*)&Zc[(size_t)t * 64 + lr * 4] =
                    *(const ushort4*)&bw[row * 68 + lr * 4];
        }
        __builtin_amdgcn_wave_barrier();

        #pragma unroll
        for (int nt = 0; nt < 4; ++nt)
            #pragma unroll
            for (int r = 0; r < 4; ++r)
                bw[(lg * 4 + r) * 68 + lr + 16 * nt] = (_Float16)accY[nt][r];
        __builtin_amdgcn_wave_barrier();
        #pragma unroll
        for (int i = 0; i < 4; ++i) {
            const int row = i * 4 + lg;
            const int t = t0 + row;
            if (t < T) {
                const float4 sv = *(const float4*)&S[(size_t)t * 64 + lr * 4];
                union { _Float16 h[4]; ushort4 u; } pb;
                const _Float16* yb = &bw[row * 68 + lr * 4];
                pb.h[0] = (_Float16)((float)yb[0] + sv.x + th.x);
                pb.h[1] = (_Float16)((float)yb[1] + sv.y + th.y);
                pb.h[2] = (_Float16)((float)yb[2] + sv.z + th.z);
                pb.h[3] = (_Float16)((float)yb[3] + sv.w + th.w);
                *(ushort4*)&base[(size_t)t * 64 + lr * 4] = pb.u;
            }
        }
        __builtin_amdgcn_wave_barrier();
    }
}

// ---------------------------------------------------------------------------
// Kernel 3 (dot2 FIR, sched_barrier-enforced ping-pong pipeline):
//   filtered[t,s] = sum_d kern[s][d-1] * Zc[t-d][s]
//   out = sigmoid(base + filtered) * W + V_o
// Load buffer X for group g+1; sched_barrier(0); compute group g from buffer
// Y. The fence defeats the compiler's load-sinking (R4-R6: VGPR pinned at 40,
// loads issued at use, all waves lockstep-stalled on the same waitcnt).
// ---------------------------------------------------------------------------
#define GROUP8(nE, kv)                                                          \
    _Pragma("unroll")                                                           \
    for (int j = 0; j < 8; ++j) {                                               \
        O[(j + 7) & 7] = __builtin_amdgcn_alignbit(nE[j], E[(j + 7) & 7], 16);  \
        uh2 kk; kk.u = kv[j];                                                   \
        _Pragma("unroll")                                                       \
        for (int i = 0; i < 8; ++i) {                                           \
            uh2 e; e.u = E[(j + i) & 7];                                        \
            uh2 o; o.u = O[(j + i) & 7];                                        \
            acc[2 * i]     = __builtin_amdgcn_fdot2(kk.h, e.h, acc[2 * i],     false); \
            acc[2 * i + 1] = __builtin_amdgcn_fdot2(kk.h, o.h, acc[2 * i + 1], false); \
        }                                                                       \
        E[j & 7] = nE[j];                                                       \
    }

#define LOADW8(nE, g) {                                                         \
    _Pragma("unroll")                                                           \
    for (int j = 0; j < 8; ++j) nE[j] = wp[q0 + (g) * 8 + 8 + j]; }

#define LOADK8(kv, g) {                                                         \
    uint4 _a = *(const uint4*)(tp0 + (g) * 8);                                  \
    uint4 _b = *(const uint4*)(tp0 + (g) * 8 + 4);                              \
    kv[0]=_a.x; kv[1]=_a.y; kv[2]=_a.z; kv[3]=_a.w;                             \
    kv[4]=_b.x; kv[5]=_b.y; kv[6]=_b.z; kv[7]=_b.w; }

__global__ __launch_bounds__(512, 3) void k_conv(
    const uint* __restrict__ krt, const _Float16* __restrict__ Zc,
    const _Float16* __restrict__ base, const float* __restrict__ W,
    const float* __restrict__ Vo, float* __restrict__ out, int T)
{
    __shared__ uint wzu[SUBS * WROW];          // 42240 B
    ushort* wzh = (ushort*)wzu;
    const int tid = threadIdx.x;
    const int t0  = blockIdx.x * BT;

    {   // stage + transpose Zc rows [t0-200, t0+BT): global [t][s] -> LDS [s][t]
        const ushort4* src = (const ushort4*)Zc;
        const int n = (BT + THIST) * (SUBS / 4);
        for (int i = tid; i < n; i += 512) {
            int r  = i >> 4;
            int c4 = i & 15;
            int g  = t0 - THIST + r;
            ushort4 v = make_ushort4(0, 0, 0, 0);
            if (g >= 0 && g < T) v = src[(size_t)g * 16 + c4];
            wzh[(4 * c4 + 0) * 2 * WROW + r] = v.x;
            wzh[(4 * c4 + 1) * 2 * WROW + r] = v.y;
            wzh[(4 * c4 + 2) * 2 * WROW + r] = v.z;
            wzh[(4 * c4 + 3) * 2 * WROW + r] = v.w;
        }
    }
    __syncthreads();

    const int s   = tid & 63;
    const int wid = tid >> 6;
    const int rt  = wid * 16;
    const int q0  = wid * 8;
    const uint* wp  = &wzu[s * WROW];
    const uint* tp0 = krt + s * 100;

    float acc[16];
    #pragma unroll
    for (int r = 0; r < 16; ++r) acc[r] = 0.f;

    uint E[8], O[8];
    #pragma unroll
    for (int i = 0; i < 8; ++i) E[i] = wp[q0 + i];
    #pragma unroll
    for (int i = 0; i < 7; ++i) O[i] = __builtin_amdgcn_alignbit(E[i + 1], E[i], 16);

    uint Ea[8], Ka[8], Eb[8], Kb[8];
    LOADW8(Ea, 0); LOADK8(Ka, 0);

    // groups 0..9: ping-pong, loads fenced one group ahead
    #pragma unroll 1
    for (int gg = 0; gg < 5; ++gg) {
        const int g = 2 * gg;
        LOADW8(Eb, g + 1); LOADK8(Kb, g + 1);
        __builtin_amdgcn_sched_barrier(0);
        GROUP8(Ea, Ka);                      // group g
        LOADW8(Ea, g + 2); LOADK8(Ka, g + 2);
        __builtin_amdgcn_sched_barrier(0);
        GROUP8(Eb, Kb);                      // group g+1
    }
    // groups 10, 11 + tail (pairs 96..99)
    LOADW8(Eb, 11); LOADK8(Kb, 11);
    __builtin_amdgcn_sched_barrier(0);
    GROUP8(Ea, Ka);                          // group 10
    {   // tail data into Ea[0..3]/Ka[0..3]
        #pragma unroll
        for (int j = 0; j < 4; ++j) Ea[j] = wp[q0 + 104 + j];
        uint4 _a = *(const uint4*)(tp0 + 96);
        Ka[0]=_a.x; Ka[1]=_a.y; Ka[2]=_a.z; Ka[3]=_a.w;
    }
    __builtin_amdgcn_sched_barrier(0);
    GROUP8(Eb, Kb);                          // group 11
    #pragma unroll
    for (int j = 0; j < 4; ++j) {            // tail: pairs 96..99
        O[(j + 7) & 7] = __builtin_amdgcn_alignbit(Ea[j], E[(j + 7) & 7], 16);
        uh2 kk; kk.u = Ka[j];
        #pragma unroll
        for (int i = 0; i < 8; ++i) {
            uh2 e; e.u = E[(j + i) & 7];
            uh2 o; o.u = O[(j + i) & 7];
            acc[2 * i]     = __builtin_amdgcn_fdot2(kk.h, e.h, acc[2 * i],     false);
            acc[2 * i + 1] = __builtin_amdgcn_fdot2(kk.h, o.h, acc[2 * i + 1], false);
        }
        E[j & 7] = Ea[j];
    }

    const float wsub = W[s];
    const float vo   = Vo[0];
    #pragma unroll
    for (int r = 0; r < 16; ++r) {
        const int t = t0 + rt + r;
        if (t < T) {
            float xin = (float)base[(size_t)t * SUBS + s] + acc[r];
            float sig = 1.0f / (1.0f + __expf(-xin));
            out[(size_t)t * SUBS + s] = fmaf(sig, wsub, vo);
        }
    }
}

// ---------------------------------------------------------------------------
extern "C" void kernel_launch(void* const* d_in, const int* in_sizes, int n_in,
                              void* d_out, int out_size, void* d_ws, size_t ws_size,
                              hipStream_t stream)
{
    const float* S     = (const float*)d_in[0];
    const float* Y     = (const float*)d_in[1];
    const float* Z     = (const float*)d_in[2];
    const float* C     = (const float*)d_in[3];
    const float* Vo    = (const float*)d_in[4];
    const float* W     = (const float*)d_in[5];
    const float* theta = (const float*)d_in[6];
    const float* K     = (const float*)d_in[7];
    const float* tau   = (const float*)d_in[8];
    const float* delta = (const float*)d_in[9];
    const int T = in_sizes[0] / SUBS;

    uint*      krt  = (uint*)d_ws;                                  // 25600 B
    _Float16*  Zc   = (_Float16*)((char*)d_ws + 32768);             // T*64*2 B
    _Float16*  base = (_Float16*)((char*)d_ws + 32768 + (size_t)T * SUBS * 2);

    k_taps<<<(NPAIR * SUBS + 255) / 256, 256, 0, stream>>>(K, tau, delta, krt);
    k_zc_base<<<(T + 127) / 128, 256, 0, stream>>>(Z, Y, S, C, theta, Zc, base, T);
    k_conv<<<(T + BT - 1) / BT, 512, 0, stream>>>(krt, Zc, base, W, Vo, (float*)d_out, T);
}